// Round 5
// baseline (277.908 us; speedup 1.0000x reference)
//
#include <hip/hip_runtime.h>
#include <hip/hip_bf16.h>
#include <stdint.h>

#define N_DIM 2048
#define BATCH_SZ 8192

typedef __bf16 bf16;
typedef __bf16 bf16x4 __attribute__((ext_vector_type(4)));
typedef __bf16 bf16x8 __attribute__((ext_vector_type(8)));
typedef float f32x4 __attribute__((ext_vector_type(4)));

// Async global->LDS, 16B per lane. LDS dest is wave-uniform base + lane*16.
__device__ __forceinline__ void gld16(const bf16* g, bf16* l) {
  __builtin_amdgcn_global_load_lds(
      (const __attribute__((address_space(1))) void*)g,
      (__attribute__((address_space(3))) void*)l, 16, 0, 0);
}

// Build Wb = bf16(W) where W = -S (so exp(W) = Q^T), Wtb = bf16(W^T) = bf16(S).
__global__ void unfold_kernel(const float* __restrict__ Sflat,
                              bf16* __restrict__ Wb,
                              bf16* __restrict__ Wtb) {
  int idx = blockIdx.x * blockDim.x + threadIdx.x;
  int i = idx >> 11;            // row
  int j = idx & (N_DIM - 1);    // col
  float v = 0.0f;               // v = S[i][j]
  if (i < j) {
    int fi = i * (N_DIM - 1) - ((i * (i - 1)) >> 1) + (j - i - 1);
    v = Sflat[fi];
  } else if (i > j) {
    int fi = j * (N_DIM - 1) - ((j * (j - 1)) >> 1) + (i - j - 1);
    v = -Sflat[fi];
  }
  Wb[idx]  = (bf16)(-v);   // W = -S
  Wtb[idx] = (bf16)(v);    // W^T = S
}

// ---------------------------------------------------------------------------
// Weight GEMM (G1/G2): C(2048x2048) = A @ Bt^T, bf16 in, fp32 acc.
//
// Theory (R4 post-mortem): at 2048^3 the operands are cache-resident and the
// kernel is LATENCY-bound, not pipeline-structure-bound (shallow vs deep
// pipeline at 2 blocks/CU differ by only 10%; 1->2 blocks/CU moved 87->75).
// Fix = occupancy: 64x64 tiles -> 1024 blocks; ring-4 LDS = 32 KB ->
// 5 blocks/CU -> 5 independent waves/SIMD (every block: 4 waves, one/SIMD).
// Whole GEMM resident at once; prefetch-3, counted vmcnt (never 0 in steady
// state), proven XOR-swizzled staging (SQ_LDS_BANK_CONFLICT = 0, R0-R4).
//
// MODE 1: O1 = bf16(acc) [W2];  O2 = bf16(I/2 - W/6 + acc/24) [B^T operand]
// MODE 2: O1 = bf16(acc + I + W)                          (Q^T)
// CAST 1: blocks with blockIdx.y >= 32 instead cast Xsrc f32 -> Xdst bf16
//         (independent HBM-streaming work overlapped with the GEMM).
// Requires: M == N == 2048 (gridDim.x == 32), K % 128 == 0.
template <int MODE, int CAST>
__global__ __launch_bounds__(256, 5) void gemm_w64(
    const bf16* __restrict__ A, const bf16* __restrict__ Bt,
    bf16* __restrict__ O1, bf16* __restrict__ O2,
    const bf16* __restrict__ Wb,
    const float* __restrict__ Xsrc, bf16* __restrict__ Xdst,
    int M, int N, int K) {
  __shared__ __align__(16) bf16 As[4 * 64 * 32];   // 16 KB (ring of 4)
  __shared__ __align__(16) bf16 Bs[4 * 64 * 32];   // 16 KB

  if (CAST && blockIdx.y >= 32) {
    // Fused cast: 256 blocks, each 16384 float4 (coalesced grid-stride).
    const int id = (blockIdx.y - 32) * 32 + blockIdx.x;   // 0..255
    const float4* src = (const float4*)Xsrc;
    bf16x4* dst = (bf16x4*)Xdst;
    const int base = id * 16384;
#pragma unroll 4
    for (int k = 0; k < 64; ++k) {
      float4 v = src[base + k * 256 + threadIdx.x];
      bf16x4 o;
      o.x = (bf16)v.x; o.y = (bf16)v.y; o.z = (bf16)v.z; o.w = (bf16)v.w;
      dst[base + k * 256 + threadIdx.x] = o;
    }
    return;
  }

  const int tid  = threadIdx.x;
  const int lane = tid & 63;
  const int wave = tid >> 6;     // 0..3
  const int wr   = wave >> 1;    // 0..1  M-half (32 rows)
  const int wc   = wave & 1;     // 0..1  N-half (32 cols)
  const int quad = lane >> 4;
  const int l16  = lane & 15;

  // Bijective XCD swizzle over the 1024 GEMM blocks.
  const int nwg    = 1024;
  const int linear = blockIdx.y * 32 + blockIdx.x;
  const int wg = (linear & 7) * (nwg >> 3) + (linear >> 3);
  const int bx = wg & 31;
  const int by = wg >> 5;
  const int m0 = by * 64;
  const int n0 = bx * 64;

  // Staging swizzle (verified conflict-free R0-R4):
  // LDS[row][c] = G[row][c ^ ((row>>1)&3)] per 8-elem segment.
  const int srow  = lane >> 2;
  const int sslot = (lane & 3) ^ ((lane >> 3) & 3);
  const bf16* gA = A  + (size_t)(m0 + wave * 16 + srow) * K + sslot * 8;
  const bf16* gB = Bt + (size_t)(n0 + wave * 16 + srow) * K + sslot * 8;
  bf16* lA = As + wave * 512;   // + buf*2048
  bf16* lB = Bs + wave * 512;

  const int NT = K >> 5;   // K-tiles of 32 (64 for K=2048)

  // Prologue: stage tiles 0,1,2 into ring buffers 0,1,2 (6 loads/thread),
  // then retire tile 0's 2 loads only (4 stay in flight).
#pragma unroll
  for (int tt = 0; tt < 3; ++tt) {
    gld16(gA + tt * 32, lA + tt * 2048);
    gld16(gB + tt * 32, lB + tt * 2048);
  }
  asm volatile("s_waitcnt vmcnt(4)" ::: "memory");
  __builtin_amdgcn_sched_barrier(0);
  __builtin_amdgcn_s_barrier();
  __builtin_amdgcn_sched_barrier(0);

  f32x4 acc[2][2] = {};
  const int rswz = (quad ^ ((l16 >> 1) & 3)) * 8;
  const int arow = wr * 32 + l16;
  const int brow = wc * 32 + l16;

#pragma unroll 1
  for (int t4 = 0; t4 < NT; t4 += 4) {
#pragma unroll
    for (int u = 0; u < 4; ++u) {
      const int t = t4 + u;
      // Stage tile t+3 into buffer (u+3)&3 (its last reads finished before
      // the boundary barrier that ended tile t-1).
      if (t + 3 < NT) {
        const int b = (u + 3) & 3;
        gld16(gA + (size_t)(t + 3) * 32, lA + b * 2048);
        gld16(gB + (size_t)(t + 3) * 32, lB + b * 2048);
      }
      const bf16* ab = As + u * 2048;
      const bf16* bb = Bs + u * 2048;
      bf16x8 af[2], bfr[2];
#pragma unroll
      for (int mi = 0; mi < 2; ++mi)
        af[mi] = *(const bf16x8*)&ab[(arow + mi * 16) * 32 + rswz];
#pragma unroll
      for (int ni = 0; ni < 2; ++ni)
        bfr[ni] = *(const bf16x8*)&bb[(brow + ni * 16) * 32 + rswz];
      __builtin_amdgcn_s_setprio(1);
#pragma unroll
      for (int mi = 0; mi < 2; ++mi)
#pragma unroll
        for (int ni = 0; ni < 2; ++ni)
          acc[mi][ni] = __builtin_amdgcn_mfma_f32_16x16x32_bf16(
              af[mi], bfr[ni], acc[mi][ni], 0, 0, 0);
      __builtin_amdgcn_s_setprio(0);
      // Boundary: retire tile t+1's 2 loads; keep t+2/t+3's in flight.
      if (t < NT - 1) {
        if (t < NT - 3)
          asm volatile("s_waitcnt vmcnt(4)" ::: "memory");
        else if (t == NT - 3)
          asm volatile("s_waitcnt vmcnt(2)" ::: "memory");
        else
          asm volatile("s_waitcnt vmcnt(0)" ::: "memory");
        __builtin_amdgcn_sched_barrier(0);
        __builtin_amdgcn_s_barrier();
        __builtin_amdgcn_sched_barrier(0);
      }
    }
  }

  // Epilogue. C/D layout: col = lane&15, row = quad*4 + reg.
#pragma unroll
  for (int mi = 0; mi < 2; ++mi) {
    const int r0 = m0 + wr * 32 + mi * 16 + quad * 4;
#pragma unroll
    for (int ni = 0; ni < 2; ++ni) {
      const int col = n0 + wc * 32 + ni * 16 + l16;
#pragma unroll
      for (int r = 0; r < 4; ++r) {
        const int row = r0 + r;
        const size_t idx = (size_t)row * N + col;
        const float v = acc[mi][ni][r];
        if (MODE == 1) {
          // v = W2[row][col]. B = I/2 + W/6 + W2/24 ->
          // B^T = I/2 - W/6 + W2/24  (W antisymmetric, W2 symmetric).
          O1[idx] = (bf16)v;
          const float w = (float)Wb[idx];
          const float d = (row == col) ? 1.0f : 0.0f;
          O2[idx] = (bf16)(0.5f * d - (1.0f / 6.0f) * w + (1.0f / 24.0f) * v);
        } else {  // MODE 2: Q^T = acc + I + W
          const float w = (float)Wb[idx];
          const float d = (row == col) ? 1.0f : 0.0f;
          O1[idx] = (bf16)(v + d + w);
        }
      }
    }
  }
}

// ---------------------------------------------------------------------------
// G3 kernel (frozen at round-1 version: best measured, 77 us, ~890 TF).
// C(MxN) f32 = A(MxK) @ Bt(NxK)^T, bf16 in. 256x256 tile, 8 waves (2Mx4N),
// BK=32, 4-deep LDS ring (128 KiB), global_load_lds staging 3 tiles ahead,
// counted vmcnt (never 0 in steady state), one raw s_barrier per K-tile,
// setprio around the MFMA cluster.
// Requires: N == gridDim.x*256 with gridDim.x == 8, K % 128 == 0, K/32 >= 4.
__global__ __launch_bounds__(512, 2) void gemm256(
    const bf16* __restrict__ A, const bf16* __restrict__ Bt,
    float* __restrict__ Cf, int M, int N, int K) {
  __shared__ __align__(16) bf16 As[4 * 256 * 32];   // 64 KB
  __shared__ __align__(16) bf16 Bs[4 * 256 * 32];   // 64 KB

  const int tid  = threadIdx.x;
  const int lane = tid & 63;
  const int wave = tid >> 6;     // 0..7
  const int wr   = wave >> 2;    // 0..1  M-half
  const int wc   = wave & 3;     // 0..3  N-quarter
  const int quad = lane >> 4;
  const int l16  = lane & 15;

  // Bijective XCD swizzle (nwg = 256 divisible by 8).
  const int nwg    = gridDim.x * gridDim.y;
  const int linear = blockIdx.y * gridDim.x + blockIdx.x;
  const int wg = (linear & 7) * (nwg >> 3) + (linear >> 3);
  const int bx = wg & 7;         // gridDim.x == 8 (N == 2048)
  const int by = wg >> 3;
  const int m0 = by * 256;
  const int n0 = bx * 256;

  const int srow  = lane >> 2;
  const int sslot = (lane & 3) ^ ((lane >> 3) & 3);
  const bf16* pA1 = A  + (size_t)(m0 + wave * 16 + srow) * K + sslot * 8;
  const bf16* pA2 = pA1 + (size_t)128 * K;
  const bf16* pB1 = Bt + (size_t)(n0 + wave * 16 + srow) * K + sslot * 8;
  const bf16* pB2 = pB1 + (size_t)128 * K;
  bf16* lA1 = As + wave * 512;          // + buf*8192
  bf16* lA2 = As + wave * 512 + 4096;
  bf16* lB1 = Bs + wave * 512;
  bf16* lB2 = Bs + wave * 512 + 4096;

  const int NT = K >> 5;   // K-tiles of 32

  // Prologue: stage tiles 0,1,2 into ring buffers 0,1,2 (12 loads/thread),
  // then wait for tile 0 only (8 loads stay in flight).
#pragma unroll
  for (int tt = 0; tt < 3; ++tt) {
    gld16(pA1 + tt * 32, lA1 + tt * 8192);
    gld16(pA2 + tt * 32, lA2 + tt * 8192);
    gld16(pB1 + tt * 32, lB1 + tt * 8192);
    gld16(pB2 + tt * 32, lB2 + tt * 8192);
  }
  asm volatile("s_waitcnt vmcnt(8)" ::: "memory");
  __builtin_amdgcn_s_barrier();
  __builtin_amdgcn_sched_barrier(0);

  f32x4 acc[8][4] = {};
  const int rswz = (quad ^ ((l16 >> 1) & 3)) * 8;  // reader swizzle (elems)
  const int arow = wr * 128 + l16;
  const int brow = wc * 64 + l16;

  size_t kpre = 96;   // element k-offset of tile t+3 at t=0

#pragma unroll 1
  for (int t4 = 0; t4 < NT; t4 += 4) {
#pragma unroll
    for (int u = 0; u < 4; ++u) {
      const int t = t4 + u;
      // Issue staging for tile t+3 -> buffer (u+3)&3.
      if (t + 3 < NT) {
        const int b = (u + 3) & 3;
        const size_t ko = kpre + (size_t)u * 32;
        gld16(pA1 + ko, lA1 + b * 8192);
        gld16(pA2 + ko, lA2 + b * 8192);
        gld16(pB1 + ko, lB1 + b * 8192);
        gld16(pB2 + ko, lB2 + b * 8192);
      }
      // Compute tile t from buffer u.
      const bf16* ab = As + u * 8192;
      const bf16* bb = Bs + u * 8192;
      bf16x8 af[8], bfr[4];
#pragma unroll
      for (int mi = 0; mi < 8; ++mi)
        af[mi] = *(const bf16x8*)&ab[(arow + mi * 16) * 32 + rswz];
#pragma unroll
      for (int ni = 0; ni < 4; ++ni)
        bfr[ni] = *(const bf16x8*)&bb[(brow + ni * 16) * 32 + rswz];
      __builtin_amdgcn_s_setprio(1);
#pragma unroll
      for (int mi = 0; mi < 8; ++mi)
#pragma unroll
        for (int ni = 0; ni < 4; ++ni)
          acc[mi][ni] = __builtin_amdgcn_mfma_f32_16x16x32_bf16(
              af[mi], bfr[ni], acc[mi][ni], 0, 0, 0);
      __builtin_amdgcn_s_setprio(0);
      // K-tile boundary: retire tile t+1's 4 loads, keep the rest in flight.
      if (t < NT - 1) {
        if (t < NT - 3)
          asm volatile("s_waitcnt vmcnt(8)" ::: "memory");
        else if (t == NT - 3)
          asm volatile("s_waitcnt vmcnt(4)" ::: "memory");
        else
          asm volatile("s_waitcnt vmcnt(0)" ::: "memory");
        __builtin_amdgcn_sched_barrier(0);
        __builtin_amdgcn_s_barrier();
        __builtin_amdgcn_sched_barrier(0);
      }
    }
    kpre += 128;
  }

  // Epilogue: C/D layout col = lane&15, row = quad*4 + reg.
#pragma unroll
  for (int mi = 0; mi < 8; ++mi) {
    const int r0 = m0 + wr * 128 + mi * 16 + quad * 4;
#pragma unroll
    for (int ni = 0; ni < 4; ++ni) {
      const int col = n0 + wc * 64 + ni * 16 + l16;
#pragma unroll
      for (int r = 0; r < 4; ++r)
        Cf[(size_t)(r0 + r) * N + col] = acc[mi][ni][r];
    }
  }
}

extern "C" void kernel_launch(void* const* d_in, const int* in_sizes, int n_in,
                              void* d_out, int out_size, void* d_ws, size_t ws_size,
                              hipStream_t stream) {
  const float* X     = (const float*)d_in[0];
  const float* Sflat = (const float*)d_in[1];
  float* out = (float*)d_out;
  char* ws = (char*)d_ws;

  // Workspace (72 MB total):
  bf16* Xb   = (bf16*)(ws);                 // 32 MB  bf16(X)
  bf16* Wb   = (bf16*)(ws + (32u << 20));   //  8 MB  bf16(W),   W = -S
  bf16* Wtb  = (bf16*)(ws + (40u << 20));   //  8 MB  bf16(W^T)
  bf16* W2b  = (bf16*)(ws + (48u << 20));   //  8 MB  bf16(W^2)
  bf16* Btm  = (bf16*)(ws + (56u << 20));   //  8 MB  bf16(B^T) operand for G2
  bf16* Qtb  = (bf16*)(ws + (64u << 20));   //  8 MB  bf16(Q^T)

  unfold_kernel<<<(N_DIM * N_DIM) / 256, 256, 0, stream>>>(Sflat, Wb, Wtb);

  // G1 (fused with X cast): 64x64 tiles -> 1024 GEMM blocks (5/CU resident)
  // + 256 cast blocks (blockIdx.y >= 32).
  gemm_w64<1, 1><<<dim3(32, 40), 256, 0, stream>>>(
      Wb, Wtb, W2b, Btm, Wb, X, Xb, N_DIM, N_DIM, N_DIM);
  // G2: Q^T = I + W + W2 @ B   (Bt operand = B^T).
  gemm_w64<2, 0><<<dim3(32, 32), 256, 0, stream>>>(
      W2b, Btm, Qtb, nullptr, Wb, nullptr, nullptr, N_DIM, N_DIM, N_DIM);
  // G3: out = X @ Q  (Bt = Q^T row-major). 256x256 tiles -> 256 blocks,
  // round-1 pipelined ring-buffer kernel (frozen).
  gemm256<<<dim3(N_DIM / 256, BATCH_SZ / 256), 512, 0, stream>>>(
      Xb, Qtb, out, BATCH_SZ, N_DIM, N_DIM);
}